// Round 6
// baseline (167.551 us; speedup 1.0000x reference)
//
#include <hip/hip_runtime.h>
#include <hip/hip_bf16.h>

#define B_DIM 16
#define T_RED 512
#define C_DIM 512
#define ROWS_PER_BLK 64

typedef float vfloat4 __attribute__((ext_vector_type(4)));

// Inclusive block scan over 256 threads (4 waves). Ends with a barrier so
// wsum can be reused by a subsequent call.
__device__ inline int block_scan256(int v, int* wsum /*>=4 ints LDS*/) {
    const int lane = threadIdx.x & 63;
    const int wid  = threadIdx.x >> 6;  // 0..3
    int s = v;
    #pragma unroll
    for (int off = 1; off < 64; off <<= 1) {
        int n = __shfl_up(s, off, 64);
        if (lane >= off) s += n;
    }
    if (lane == 63) wsum[wid] = s;
    __syncthreads();
    int add = 0;
    #pragma unroll
    for (int w = 0; w < 4; ++w)
        if (w < wid) add += wsum[w];
    int out = s + add;
    __syncthreads();  // protect wsum for reuse
    return out;
}

// Fused kernel, 64 output rows per block, XCD-swizzled chunk order.
// Each block recomputes its batch's stable-compaction + cumsum (512 durations,
// 2/thread), binary-searches segments for its 64 rows, then gathers + NT-stores.
__global__ __launch_bounds__(256) void scatter_fused(
        const vfloat4* __restrict__ x4,
        const int2* __restrict__ dur2,
        vfloat4* __restrict__ out4,
        float* __restrict__ out_mask,
        int max_len, int chunks_per_batch) {
    // XCD swizzle: round-robin dispatch sends linear block i to XCD i%8.
    // Remap so XCD k owns a CONTIGUOUS chunk range -> contiguous ~2 MB slice
    // of pooled_x resident in that XCD's 4 MiB L2.
    const int tc  = gridDim.x;
    const int g   = tc >> 3;             // chunks per XCD (floor)
    const int lin = blockIdx.x;
    const int sw  = (lin < (g << 3)) ? ((lin & 7) * g + (lin >> 3)) : lin;

    const int b    = sw / chunks_per_batch;
    const int base = (sw - b * chunks_per_batch) * ROWS_PER_BLK;
    const int tid  = threadIdx.x;  // 0..255

    __shared__ int dcomp[T_RED];
    __shared__ int csum[T_RED];
    __shared__ int wsum[4];
    __shared__ int ls[ROWS_PER_BLK];

    // Load 2 durations per thread (32 KB total across grid; L2-resident).
    const int2 dd = dur2[b * (T_RED / 2) + tid];
    const int d0 = dd.x, d1 = dd.y;
    const int f0 = (d0 > 0) ? 1 : 0;
    const int f1 = (d1 > 0) ? 1 : 0;

    // Scan 1: stable-compaction positions.
    const int S1 = block_scan256(f0 + f1, wsum);
    const int excl = S1 - f0 - f1;
    dcomp[2 * tid]     = 0;
    dcomp[2 * tid + 1] = 0;
    __syncthreads();
    if (f0) dcomp[excl] = d0;
    if (f1) dcomp[excl + f0] = d1;
    __syncthreads();

    // Scan 2: inclusive cumsum of compacted durations.
    const int c0 = dcomp[2 * tid];
    const int c1 = dcomp[2 * tid + 1];
    const int S2 = block_scan256(c0 + c1, wsum);
    csum[2 * tid]     = S2 - c1;
    csum[2 * tid + 1] = S2;
    __syncthreads();

    const int total = csum[T_RED - 1];  // == target_T[b]

    // Threads 0..63: segment binary search for this block's 64 rows + mask.
    if (tid < ROWS_PER_BLK) {
        const int t = base + tid;
        int src = -1;
        if (t < max_len && t < total) {
            int idx = 0;  // count of csum entries <= t (searchsorted right)
            #pragma unroll
            for (int w = 256; w >= 1; w >>= 1) {
                const int cand = idx + w;
                if (cand <= T_RED && csum[cand - 1] <= t) idx = cand;
            }
            const int seg = (idx < T_RED - 1) ? idx : (T_RED - 1);
            src = b * T_RED + seg;
        }
        if (t < max_len) {
            ls[tid] = src;
            __builtin_nontemporal_store((src >= 0) ? 0.0f : 1.0f,
                                        &out_mask[(size_t)b * max_len + t]);
        }
    }
    __syncthreads();

    // Gather + streaming store: 64 rows x 512 floats. 2 rows per pass,
    // inner unroll of 8 passes -> 8 independent load/store chains.
    const int c4   = tid & 127;
    const int half = tid >> 7;
    for (int q = 0; q < 4; ++q) {
        #pragma unroll
        for (int p = 0; p < 8; ++p) {
            const int lr = q * 16 + p * 2 + half;
            const int t  = base + lr;
            if (t < max_len) {
                const int s = ls[lr];
                vfloat4 v = (vfloat4)(0.0f);
                if (s >= 0) v = x4[(size_t)s * (C_DIM / 4) + c4];
                __builtin_nontemporal_store(
                    v, &out4[((size_t)b * max_len + t) * (C_DIM / 4) + c4]);
            }
        }
    }
}

extern "C" void kernel_launch(void* const* d_in, const int* in_sizes, int n_in,
                              void* d_out, int out_size, void* d_ws, size_t ws_size,
                              hipStream_t stream) {
    const float* pooled_x  = (const float*)d_in[0];
    const int*   durations = (const int*)d_in[1];

    // out_size = B*max_len*C + B*max_len  ->  max_len = out_size / (B*(C+1))
    const int max_len = out_size / (B_DIM * (C_DIM + 1));

    float* out_x    = (float*)d_out;
    float* out_mask = out_x + (size_t)B_DIM * max_len * C_DIM;

    const int cpb = (max_len + ROWS_PER_BLK - 1) / ROWS_PER_BLK;

    scatter_fused<<<B_DIM * cpb, 256, 0, stream>>>(
        (const vfloat4*)pooled_x, (const int2*)durations,
        (vfloat4*)out_x, out_mask, max_len, cpb);
}

// Round 7
// 160.118 us; speedup vs baseline: 1.0464x; 1.0464x over previous
//
#include <hip/hip_runtime.h>
#include <hip/hip_bf16.h>

#define B_DIM 16
#define T_RED 512
#define C_DIM 512
#define ROWS_PER_BLK 16

typedef float vfloat4 __attribute__((ext_vector_type(4)));

// Inclusive block scan over 256 threads (4 waves). Ends with a barrier so
// wsum can be reused by a subsequent call.
__device__ inline int block_scan256(int v, int* wsum /*>=4 ints LDS*/) {
    const int lane = threadIdx.x & 63;
    const int wid  = threadIdx.x >> 6;  // 0..3
    int s = v;
    #pragma unroll
    for (int off = 1; off < 64; off <<= 1) {
        int n = __shfl_up(s, off, 64);
        if (lane >= off) s += n;
    }
    if (lane == 63) wsum[wid] = s;
    __syncthreads();
    int add = 0;
    #pragma unroll
    for (int w = 0; w < 4; ++w)
        if (w < wid) add += wsum[w];
    int out = s + add;
    __syncthreads();  // protect wsum for reuse
    return out;
}

// Fused kernel: each block recomputes its batch's stable-compaction + cumsum
// (512 durations, 2 per thread), binary-searches segments for its 16 output
// rows, then does the coalesced gather + nontemporal store.
// grid = (ceil(max_len/16), B), block = 256.
__global__ __launch_bounds__(256) void scatter_fused(
        const vfloat4* __restrict__ x4,
        const int2* __restrict__ dur2,     // durations viewed as int2
        vfloat4* __restrict__ out4,
        float* __restrict__ out_mask,
        int max_len) {
    const int b    = blockIdx.y;
    const int base = blockIdx.x * ROWS_PER_BLK;   // row offset within batch
    const int tid  = threadIdx.x;                 // 0..255

    __shared__ int dcomp[T_RED];
    __shared__ int csum[T_RED];
    __shared__ int wsum[4];
    __shared__ int ls[ROWS_PER_BLK];

    // Load 2 durations per thread (coalesced 8B; 32 KB total stays in L2).
    const int2 dd = dur2[b * (T_RED / 2) + tid];
    const int d0 = dd.x, d1 = dd.y;
    const int f0 = (d0 > 0) ? 1 : 0;
    const int f1 = (d1 > 0) ? 1 : 0;

    // Scan 1: stable-compaction positions.
    const int S1 = block_scan256(f0 + f1, wsum);   // inclusive flag count
    const int excl = S1 - f0 - f1;
    dcomp[2 * tid]     = 0;
    dcomp[2 * tid + 1] = 0;
    __syncthreads();
    if (f0) dcomp[excl] = d0;
    if (f1) dcomp[excl + f0] = d1;
    __syncthreads();

    // Scan 2: inclusive cumsum of compacted durations.
    const int c0 = dcomp[2 * tid];
    const int c1 = dcomp[2 * tid + 1];
    const int S2 = block_scan256(c0 + c1, wsum);
    csum[2 * tid]     = S2 - c1;
    csum[2 * tid + 1] = S2;
    __syncthreads();

    const int total = csum[T_RED - 1];  // == target_T[b]

    // Threads 0..15: binary-search segment for each of this block's rows.
    if (tid < ROWS_PER_BLK) {
        const int t = base + tid;
        int src = -1;
        if (t < max_len && t < total) {
            // idx = count of csum entries <= t  (searchsorted right)
            int idx = 0;
            #pragma unroll
            for (int w = 256; w >= 1; w >>= 1) {
                const int cand = idx + w;
                if (cand <= T_RED && csum[cand - 1] <= t) idx = cand;
            }
            const int seg = (idx < T_RED - 1) ? idx : (T_RED - 1);
            src = b * T_RED + seg;
        }
        if (t < max_len) {
            ls[tid] = src;
            out_mask[(size_t)b * max_len + t] = (src >= 0) ? 0.0f : 1.0f;
        }
    }
    __syncthreads();

    // Gather + streaming store: 16 rows x 512 floats, 8 independent chains.
    const int c4   = tid & 127;
    const int half = tid >> 7;
    #pragma unroll
    for (int p = 0; p < 8; ++p) {
        const int lr = 2 * p + half;
        const int t  = base + lr;
        if (t < max_len) {
            const int s = ls[lr];
            vfloat4 v = (vfloat4)(0.0f);
            if (s >= 0) v = x4[(size_t)s * (C_DIM / 4) + c4];
            __builtin_nontemporal_store(
                v, &out4[((size_t)b * max_len + t) * (C_DIM / 4) + c4]);
        }
    }
}

extern "C" void kernel_launch(void* const* d_in, const int* in_sizes, int n_in,
                              void* d_out, int out_size, void* d_ws, size_t ws_size,
                              hipStream_t stream) {
    const float* pooled_x  = (const float*)d_in[0];
    const int*   durations = (const int*)d_in[1];

    // out_size = B*max_len*C + B*max_len  ->  max_len = out_size / (B*(C+1))
    const int max_len = out_size / (B_DIM * (C_DIM + 1));

    float* out_x    = (float*)d_out;
    float* out_mask = out_x + (size_t)B_DIM * max_len * C_DIM;

    dim3 grid((max_len + ROWS_PER_BLK - 1) / ROWS_PER_BLK, B_DIM);
    scatter_fused<<<grid, 256, 0, stream>>>(
        (const vfloat4*)pooled_x, (const int2*)durations,
        (vfloat4*)out_x, out_mask, max_len);
}